// Round 1
// baseline (182.405 us; speedup 1.0000x reference)
//
#include <hip/hip_runtime.h>

#define L_LAYERS 783
#define B_BATCH  8192
#define N_SITES  784
#define K_KRAUS  16

// ---------------------------------------------------------------------------
// Kernel 1: build per-layer superoperator T.
// T[l][cd][m][i2j2] complex, cd = c*2+d, m = i1*2+j1, i2j2 = i2*2+j2.
// T = sum_{a,k} K_k[2a+c, 2*i1+i2] * conj(K_k[2a+d, 2*j1+j2])
// Layout: 128 floats per layer: offset l*128 + (cd*16 + m*4 + i2j2)*2 (+1 imag)
// ---------------------------------------------------------------------------
__global__ void build_T(const float* __restrict__ kr, const float* __restrict__ ki,
                        float* __restrict__ T) {
    int l = blockIdx.x;
    int e = threadIdx.x;            // 0..63
    int i2j2 = e & 3;
    int m    = (e >> 2) & 3;
    int cd   = (e >> 4) & 3;
    int c = cd >> 1, d = cd & 1;
    int i1 = m >> 1, j1 = m & 1;
    int i2 = i2j2 >> 1, j2 = i2j2 & 1;
    int p1 = 2 * i1 + i2;
    int p2 = 2 * j1 + j2;
    const float* krl = kr + (size_t)l * (K_KRAUS * 16);
    const float* kil = ki + (size_t)l * (K_KRAUS * 16);
    float ar = 0.f, ai = 0.f;
    for (int k = 0; k < K_KRAUS; ++k) {
        #pragma unroll
        for (int a = 0; a < 2; ++a) {
            int r1 = 2 * a + c;
            int r2 = 2 * a + d;
            float k1r = krl[k * 16 + r1 * 4 + p1];
            float k1i = kil[k * 16 + r1 * 4 + p1];
            float k2r = krl[k * 16 + r2 * 4 + p2];
            float k2i = kil[k * 16 + r2 * 4 + p2];
            // K1 * conj(K2)
            ar += k1r * k2r + k1i * k2i;
            ai += k1i * k2r - k1r * k2i;
        }
    }
    T[(size_t)l * 128 + e * 2 + 0] = ar;
    T[(size_t)l * 128 + e * 2 + 1] = ai;
}

// ---------------------------------------------------------------------------
// Kernel 2: per (batch, segment) compute the 4x4 complex transfer-matrix
// product P_seg = W_{le-1} * ... * W_{ls}, where
//   W[cd][m] = sum_{i2j2} T[l][cd][m][i2j2] * xx[i2j2],
//   xx = outer(x,x)/|x|^2 with x = X[b, l+1, :].
// lane = batch element -> T address is wave-uniform (scalar-load friendly).
// ---------------------------------------------------------------------------
__global__ void __launch_bounds__(256)
seg_kernel(const float* __restrict__ X, const float* __restrict__ T,
           float* __restrict__ P, int G, int seg_len) {
    int b = blockIdx.x * blockDim.x + threadIdx.x;   // batch element
    int s = blockIdx.y;                              // segment
    int ls = s * seg_len;       if (ls > L_LAYERS) ls = L_LAYERS;
    int le = ls + seg_len;      if (le > L_LAYERS) le = L_LAYERS;

    float pr[4][4], pi[4][4];
    #pragma unroll
    for (int r = 0; r < 4; ++r)
        #pragma unroll
        for (int c = 0; c < 4; ++c) { pr[r][c] = (r == c) ? 1.f : 0.f; pi[r][c] = 0.f; }

    const float* xp = X + (size_t)b * (N_SITES * 2);

    for (int l = ls; l < le; ++l) {
        float x0 = xp[(l + 1) * 2 + 0];
        float x1 = xp[(l + 1) * 2 + 1];
        float nrm = x0 * x0 + x1 * x1;
        float inv = 1.0f / nrm;
        float xx0 = x0 * x0 * inv;     // i2j2 = 00
        float xx1 = x0 * x1 * inv;     // i2j2 = 01 and 10
        float xx3 = x1 * x1 * inv;     // i2j2 = 11

        const float* tl = T + (size_t)l * 128;
        float wr[4][4], wi[4][4];
        #pragma unroll
        for (int cd = 0; cd < 4; ++cd) {
            #pragma unroll
            for (int m = 0; m < 4; ++m) {
                const float* te = tl + cd * 32 + m * 8;
                float t0r = te[0], t0i = te[1];
                float t1r = te[2], t1i = te[3];
                float t2r = te[4], t2i = te[5];
                float t3r = te[6], t3i = te[7];
                wr[cd][m] = t0r * xx0 + (t1r + t2r) * xx1 + t3r * xx3;
                wi[cd][m] = t0i * xx0 + (t1i + t2i) * xx1 + t3i * xx3;
            }
        }
        // P = W * P (complex 4x4), column-wise so no full copy of P needed
        #pragma unroll
        for (int j = 0; j < 4; ++j) {
            float cr[4], ci[4];
            #pragma unroll
            for (int r = 0; r < 4; ++r) {
                float sr = 0.f, si = 0.f;
                #pragma unroll
                for (int m2 = 0; m2 < 4; ++m2) {
                    sr += wr[r][m2] * pr[m2][j] - wi[r][m2] * pi[m2][j];
                    si += wr[r][m2] * pi[m2][j] + wi[r][m2] * pr[m2][j];
                }
                cr[r] = sr; ci[r] = si;
            }
            #pragma unroll
            for (int r = 0; r < 4; ++r) { pr[r][j] = cr[r]; pi[r][j] = ci[r]; }
        }
    }

    float* pp = P + ((size_t)b * G + s) * 32;
    #pragma unroll
    for (int r = 0; r < 4; ++r)
        #pragma unroll
        for (int c = 0; c < 4; ++c) {
            pp[(r * 4 + c) * 2 + 0] = pr[r][c];
            pp[(r * 4 + c) * 2 + 1] = pi[r][c];
        }
}

// ---------------------------------------------------------------------------
// Kernel 3: combine — sigma0 from X[b,0,:], apply the G segment matrices in
// order, output real(sigma[0][0]).
// ---------------------------------------------------------------------------
__global__ void __launch_bounds__(256)
combine_kernel(const float* __restrict__ X, const float* __restrict__ P,
               float* __restrict__ out, int G) {
    int b = blockIdx.x * blockDim.x + threadIdx.x;
    const float* xp = X + (size_t)b * (N_SITES * 2);
    float x0 = xp[0], x1 = xp[1];
    float inv = 1.0f / (x0 * x0 + x1 * x1);
    float sr[4], si[4];
    sr[0] = x0 * x0 * inv;            // sigma[i1][j1], m = i1*2+j1
    sr[1] = x0 * x1 * inv;
    sr[2] = sr[1];
    sr[3] = x1 * x1 * inv;
    si[0] = si[1] = si[2] = si[3] = 0.f;

    for (int s = 0; s < G; ++s) {
        const float* pp = P + ((size_t)b * G + s) * 32;
        float nr[4], ni[4];
        #pragma unroll
        for (int r = 0; r < 4; ++r) {
            float ar = 0.f, ai = 0.f;
            #pragma unroll
            for (int m = 0; m < 4; ++m) {
                float prc = pp[(r * 4 + m) * 2 + 0];
                float pic = pp[(r * 4 + m) * 2 + 1];
                ar += prc * sr[m] - pic * si[m];
                ai += prc * si[m] + pic * sr[m];
            }
            nr[r] = ar; ni[r] = ai;
        }
        #pragma unroll
        for (int r = 0; r < 4; ++r) { sr[r] = nr[r]; si[r] = ni[r]; }
    }
    out[b] = sr[0];
}

// ---------------------------------------------------------------------------
extern "C" void kernel_launch(void* const* d_in, const int* in_sizes, int n_in,
                              void* d_out, int out_size, void* d_ws, size_t ws_size,
                              hipStream_t stream) {
    const float* X  = (const float*)d_in[0];
    const float* kr = (const float*)d_in[1];
    const float* ki = (const float*)d_in[2];
    float* out = (float*)d_out;

    float* T = (float*)d_ws;
    const size_t Tbytes = (size_t)L_LAYERS * 128 * sizeof(float);   // 400,896 B
    float* P = (float*)((char*)d_ws + Tbytes);

    // choose number of segments that fits in workspace (prefer 16)
    const size_t perG = (size_t)B_BATCH * 32 * sizeof(float);       // 1 MiB per segment
    int G = 16;
    if (ws_size > Tbytes) {
        size_t maxg = (ws_size - Tbytes) / perG;
        if (maxg < (size_t)G) G = (int)maxg;
    }
    if (G < 1) G = 1;
    int seg_len = (L_LAYERS + G - 1) / G;

    build_T<<<L_LAYERS, 64, 0, stream>>>(kr, ki, T);

    dim3 grid(B_BATCH / 256, G);
    seg_kernel<<<grid, 256, 0, stream>>>(X, T, P, G, seg_len);

    combine_kernel<<<B_BATCH / 256, 256, 0, stream>>>(X, P, out, G);
}

// Round 2
// 100.657 us; speedup vs baseline: 1.8121x; 1.8121x over previous
//
#include <hip/hip_runtime.h>

#define L_LAYERS 783
#define B_BATCH  8192
#define N_SITES  784
#define K_KRAUS  16

// ---------------------------------------------------------------------------
// Hermitian-reduced formulation.
// State v = (s00, s11, u, w) where sigma = [[s00, u+iw], [u-iw, s11]].
// Per layer l the map v -> v' is a REAL 4x4 matrix R, itself linear in the
// input-outer-product values (xx0, xx1, xx3) = (x0^2, x0*x1, x1^2)/|x|^2:
//   R[row][col] = A[row][col]*xx0 + Bc[row][col]*xx1 + Cc[row][col]*xx3
// Kernel 1 computes the 48 floats per layer.
// Tc layout (SoA for vector LDS reads): l*48 + qq*16 + (row*4+col), qq=0(A),1(B),2(C)
// ---------------------------------------------------------------------------
__device__ inline void t_elem(const float* __restrict__ krl, const float* __restrict__ kil,
                              int c, int d, int m, int q, float& tr, float& ti) {
    // T[cd][m][q] = sum_{k,a} K_k[2a+c][2*i1+i2] * conj(K_k[2a+d][2*j1+j2])
    int i1 = m >> 1, j1 = m & 1, i2 = q >> 1, j2 = q & 1;
    int p1 = 2 * i1 + i2, p2 = 2 * j1 + j2;
    float ar = 0.f, ai = 0.f;
    #pragma unroll 4
    for (int k = 0; k < K_KRAUS; ++k) {
        #pragma unroll
        for (int a = 0; a < 2; ++a) {
            int r1 = k * 16 + (2 * a + c) * 4 + p1;
            int r2 = k * 16 + (2 * a + d) * 4 + p2;
            float k1r = krl[r1], k1i = kil[r1];
            float k2r = krl[r2], k2i = kil[r2];
            ar += k1r * k2r + k1i * k2i;      // K1 * conj(K2)
            ai += k1i * k2r - k1r * k2i;
        }
    }
    tr = ar; ti = ai;
}

__global__ void build_T(const float* __restrict__ kr, const float* __restrict__ ki,
                        float* __restrict__ Tc) {
    int g = blockIdx.x * blockDim.x + threadIdx.x;
    if (g >= L_LAYERS * 16) return;
    int l  = g >> 4;
    int rc = g & 15;
    int row = rc >> 2, col = rc & 3;
    // output rows: 0 -> Re sigma'[0][0] (cd=0), 1 -> Re sigma'[1][1] (cd=3),
    //              2 -> Re sigma'[0][1] (cd=1), 3 -> Im sigma'[0][1] (cd=1)
    int cd = (row == 0) ? 0 : (row == 1) ? 3 : 1;
    int c = cd >> 1, d = cd & 1;
    const float* krl = kr + (size_t)l * (K_KRAUS * 16);
    const float* kil = ki + (size_t)l * (K_KRAUS * 16);

    // column combos over sigma components:
    //   col0 <- s00: m=0 ; col1 <- s11: m=3 ; col2 <- u: m=1 + m=2 ;
    //   col3 <- w: i*(m=1 - m=2)
    float Ur[4], Ui[4];
    for (int q = 0; q < 4; ++q) {
        float ur, ui;
        if (col == 0)      { t_elem(krl, kil, c, d, 0, q, ur, ui); }
        else if (col == 1) { t_elem(krl, kil, c, d, 3, q, ur, ui); }
        else {
            float t1r, t1i, t2r, t2i;
            t_elem(krl, kil, c, d, 1, q, t1r, t1i);
            t_elem(krl, kil, c, d, 2, q, t2r, t2i);
            if (col == 2) { ur = t1r + t2r; ui = t1i + t2i; }
            else          { ur = -(t1i - t2i); ui = t1r - t2r; }   // i*(T1-T2)
        }
        Ur[q] = ur; Ui[q] = ui;
    }
    // xx is symmetric: q=1 and q=2 share the value xx1 -> combine.
    float c0, c1, c2;
    if (row == 3) { c0 = Ui[0]; c1 = Ui[1] + Ui[2]; c2 = Ui[3]; }
    else          { c0 = Ur[0]; c1 = Ur[1] + Ur[2]; c2 = Ur[3]; }
    float* o = Tc + (size_t)l * 48;
    o[0 * 16 + rc] = c0;
    o[1 * 16 + rc] = c1;
    o[2 * 16 + rc] = c2;
}

// ---------------------------------------------------------------------------
// Kernel 2: per (batch, segment) product of real 4x4 transfer matrices.
// Tc slice for the segment staged in LDS (wave-uniform broadcast reads).
// ---------------------------------------------------------------------------
__global__ void __launch_bounds__(256)
seg_kernel(const float* __restrict__ X, const float* __restrict__ Tc,
           float* __restrict__ P, int seg_len) {
    extern __shared__ float lds[];
    int b = blockIdx.x * blockDim.x + threadIdx.x;   // batch element
    int s = blockIdx.y;                              // segment
    int ls = s * seg_len;  if (ls > L_LAYERS) ls = L_LAYERS;
    int le = ls + seg_len; if (le > L_LAYERS) le = L_LAYERS;

    int cnt = (le - ls) * 48;
    for (int i = threadIdx.x; i < cnt; i += 256) lds[i] = Tc[(size_t)ls * 48 + i];
    __syncthreads();

    const float* xp = X + (size_t)b * (N_SITES * 2);

    float pA[16], pB[16];
    #pragma unroll
    for (int i = 0; i < 16; ++i) pA[i] = (i % 5 == 0) ? 1.f : 0.f;

#define TSTEP(SRC, DST, LIDX)                                                   \
    {                                                                           \
        float x0 = xp[((LIDX) + 1) * 2 + 0];                                    \
        float x1 = xp[((LIDX) + 1) * 2 + 1];                                    \
        float inv = 1.0f / (x0 * x0 + x1 * x1);                                 \
        float xx0 = x0 * x0 * inv, xx1 = x0 * x1 * inv, xx3 = x1 * x1 * inv;    \
        const float* tc = lds + ((LIDX) - ls) * 48;                             \
        float R[16];                                                            \
        _Pragma("unroll")                                                       \
        for (int e = 0; e < 16; ++e)                                            \
            R[e] = tc[e] * xx0 + tc[16 + e] * xx1 + tc[32 + e] * xx3;           \
        _Pragma("unroll")                                                       \
        for (int r = 0; r < 4; ++r) {                                           \
            _Pragma("unroll")                                                   \
            for (int cc = 0; cc < 4; ++cc)                                      \
                DST[r * 4 + cc] = R[r * 4 + 0] * SRC[0 * 4 + cc]                \
                                + R[r * 4 + 1] * SRC[1 * 4 + cc]                \
                                + R[r * 4 + 2] * SRC[2 * 4 + cc]                \
                                + R[r * 4 + 3] * SRC[3 * 4 + cc];               \
        }                                                                       \
    }

    int l = ls;
    for (; l + 1 < le; l += 2) {
        TSTEP(pA, pB, l);
        TSTEP(pB, pA, l + 1);
    }
    if (l < le) {                       // odd tail (uniform branch)
        TSTEP(pA, pB, l);
        #pragma unroll
        for (int i = 0; i < 16; ++i) pA[i] = pB[i];
    }
#undef TSTEP

    float* pp = P + ((size_t)s * B_BATCH + b) * 16;
    #pragma unroll
    for (int i = 0; i < 16; ++i) pp[i] = pA[i];
}

// ---------------------------------------------------------------------------
// Kernel 3: chain the G segment matrices against the initial state,
// output v0 = real(sigma[0][0]).
// ---------------------------------------------------------------------------
__global__ void __launch_bounds__(256)
combine_kernel(const float* __restrict__ X, const float* __restrict__ P,
               float* __restrict__ out, int G) {
    int b = blockIdx.x * blockDim.x + threadIdx.x;
    const float* xp = X + (size_t)b * (N_SITES * 2);
    float x0 = xp[0], x1 = xp[1];
    float inv = 1.0f / (x0 * x0 + x1 * x1);
    float v0 = x0 * x0 * inv;   // s00
    float v1 = x1 * x1 * inv;   // s11
    float v2 = x0 * x1 * inv;   // u
    float v3 = 0.f;             // w

    #pragma unroll 4
    for (int s = 0; s < G; ++s) {
        const float* pp = P + ((size_t)s * B_BATCH + b) * 16;
        float m[16];
        #pragma unroll
        for (int i = 0; i < 16; ++i) m[i] = pp[i];
        float n0 = m[0]  * v0 + m[1]  * v1 + m[2]  * v2 + m[3]  * v3;
        float n1 = m[4]  * v0 + m[5]  * v1 + m[6]  * v2 + m[7]  * v3;
        float n2 = m[8]  * v0 + m[9]  * v1 + m[10] * v2 + m[11] * v3;
        float n3 = m[12] * v0 + m[13] * v1 + m[14] * v2 + m[15] * v3;
        v0 = n0; v1 = n1; v2 = n2; v3 = n3;
    }
    out[b] = v0;
}

// ---------------------------------------------------------------------------
extern "C" void kernel_launch(void* const* d_in, const int* in_sizes, int n_in,
                              void* d_out, int out_size, void* d_ws, size_t ws_size,
                              hipStream_t stream) {
    const float* X  = (const float*)d_in[0];
    const float* kr = (const float*)d_in[1];
    const float* ki = (const float*)d_in[2];
    float* out = (float*)d_out;

    float* Tc = (float*)d_ws;
    size_t Tb = (size_t)L_LAYERS * 48 * sizeof(float);      // 150,336 B
    size_t Tb_al = (Tb + 255) & ~(size_t)255;
    float* P = (float*)((char*)d_ws + Tb_al);

    // prefer 64 segments (2048 blocks, 8 blocks/CU); clamp to workspace
    int G = 64;
    const size_t perG = (size_t)B_BATCH * 16 * sizeof(float);   // 512 KiB/segment
    if (ws_size > Tb_al) {
        size_t mg = (ws_size - Tb_al) / perG;
        if (mg < (size_t)G) G = (int)mg;
    }
    if (G < 1) G = 1;
    int seg_len = (L_LAYERS + G - 1) / G;

    build_T<<<(L_LAYERS * 16 + 255) / 256, 256, 0, stream>>>(kr, ki, Tc);

    dim3 grid(B_BATCH / 256, G);
    size_t shbytes = (size_t)seg_len * 48 * sizeof(float);
    seg_kernel<<<grid, 256, shbytes, stream>>>(X, Tc, P, seg_len);

    combine_kernel<<<B_BATCH / 256, 256, 0, stream>>>(X, P, out, G);
}